// Round 9
// baseline (310.714 us; speedup 1.0000x reference)
//
#include <hip/hip_runtime.h>
#include <hip/hip_bf16.h>

typedef __hip_bfloat16 bf16;

#define NGRAPH 128
#define MAXNB 256      // max coarse buckets (N <= 65536); nb = ceil(N/256)
#define BCAP 8192      // LDS staging capacity per bucket (avg bucket = 4096 edges)

// ---------------- B1: coarse bucket histogram (dst >> 8) ----------------
__global__ __launch_bounds__(256) void bucket_count_kernel(const int* __restrict__ ei,
                                                           int* __restrict__ bucket_cnt,
                                                           int E, int N, int nb) {
    __shared__ int hist[MAXNB];
    for (int i = threadIdx.x; i < nb; i += 256) hist[i] = 0;
    __syncthreads();
    int stride = gridDim.x * 256;
    for (int e = blockIdx.x * 256 + threadIdx.x; e < E; e += stride) {
        int d = ei[E + e];
        d = max(0, min(d, N - 1));
        atomicAdd(&hist[d >> 8], 1);
    }
    __syncthreads();
    for (int i = threadIdx.x; i < nb; i += 256) {
        int c = hist[i];
        if (c) atomicAdd(&bucket_cnt[i], c);
    }
}

// ---------------- B2: scan bucket counts -> bucket_off, init bucket_cur ----------------
__global__ __launch_bounds__(256) void bucket_scan_kernel(const int* __restrict__ bucket_cnt,
                                                          int* __restrict__ bucket_off,
                                                          int* __restrict__ bucket_cur, int nb) {
    __shared__ int tmp[256];
    int tid = threadIdx.x;
    int v = (tid < nb) ? bucket_cnt[tid] : 0;
    tmp[tid] = v;
    __syncthreads();
    for (int off = 1; off < 256; off <<= 1) {
        int t = (tid >= off) ? tmp[tid - off] : 0;
        __syncthreads();
        tmp[tid] += t;
        __syncthreads();
    }
    int excl = tmp[tid] - v;
    if (tid < nb) { bucket_off[tid] = excl; bucket_cur[tid] = excl; }
    if (tid == nb - 1) bucket_off[nb] = excl + v;   // = E
}

// ---------------- B3: scatter edges into bucket-contiguous pair buffer ----------------
__global__ __launch_bounds__(256) void bucket_scatter_kernel(const int* __restrict__ ei,
                                                             int* __restrict__ bucket_cur,
                                                             int2* __restrict__ pairbuf,
                                                             int E, int N, int nb) {
    __shared__ int hist[MAXNB];
    int nwg = gridDim.x;
    int chunk = (E + nwg - 1) / nwg;
    int e0 = blockIdx.x * chunk;
    int e1 = e0 + chunk; if (e1 > E) e1 = E;
    if (e0 >= e1) return;
    for (int i = threadIdx.x; i < nb; i += 256) hist[i] = 0;
    __syncthreads();
    // pass 1: count chunk edges per bucket
    for (int e = e0 + threadIdx.x; e < e1; e += 256) {
        int d = ei[E + e];
        d = max(0, min(d, N - 1));
        atomicAdd(&hist[d >> 8], 1);
    }
    __syncthreads();
    // reserve global ranges: hist[i] becomes this WG's running cursor
    for (int i = threadIdx.x; i < nb; i += 256) {
        int c = hist[i];
        hist[i] = c ? atomicAdd(&bucket_cur[i], c) : 0;
    }
    __syncthreads();
    // pass 2: append (src,dst) pairs
    for (int e = e0 + threadIdx.x; e < e1; e += 256) {
        int s = ei[e];     s = max(0, min(s, N - 1));
        int d = ei[E + e]; d = max(0, min(d, N - 1));
        int pos = atomicAdd(&hist[d >> 8], 1);
        pairbuf[pos] = make_int2(s, d);
    }
}

// ---------------- B4: per-bucket degree + dinv + row_start + counting sort ----------------
__global__ __launch_bounds__(256) void bucket_build_kernel(const int2* __restrict__ pairbuf,
                                                           const int* __restrict__ bucket_off,
                                                           int* __restrict__ row_start,
                                                           float* __restrict__ dinv,
                                                           int* __restrict__ csr_src,
                                                           int E, int N, int nb) {
    __shared__ int deg_l[256];
    __shared__ int cur_l[256];
    __shared__ int stage[BCAP];
    int b = blockIdx.x;              // grid = nb
    int node0 = b << 8;
    int nn = N - node0; if (nn > 256) nn = 256;
    int p0 = bucket_off[b], p1 = bucket_off[b + 1];
    int ne = p1 - p0;
    int tid = threadIdx.x;
    deg_l[tid] = 0;
    __syncthreads();
    for (int i = p0 + tid; i < p1; i += 256) {
        int d = pairbuf[i].y;        // in [node0, node0+nn)
        atomicAdd(&deg_l[d - node0], 1);
    }
    __syncthreads();
    int v = deg_l[tid];
    for (int off = 1; off < 256; off <<= 1) {
        int t = (tid >= off) ? deg_l[tid - off] : 0;
        __syncthreads();
        deg_l[tid] += t;
        __syncthreads();
    }
    int excl = deg_l[tid] - v;
    if (tid < nn) {
        row_start[node0 + tid] = p0 + excl;
        dinv[node0 + tid] = rsqrtf((float)(v + 1));   // +1 self loop
    }
    if (b == nb - 1 && tid == nn - 1) row_start[N] = p0 + excl + v;   // = E
    cur_l[tid] = excl;
    __syncthreads();
    if (ne <= BCAP) {
        for (int i = p0 + tid; i < p1; i += 256) {
            int2 pr = pairbuf[i];
            int pos = atomicAdd(&cur_l[pr.y - node0], 1);
            stage[pos] = pr.x;
        }
        __syncthreads();
        for (int i = tid; i < ne; i += 256) csr_src[p0 + i] = stage[i];
    } else {
        // statistically-never fallback (bucket > BCAP edges): direct scatter
        for (int i = p0 + tid; i < p1; i += 256) {
            int2 pr = pairbuf[i];
            int pos = atomicAdd(&cur_l[pr.y - node0], 1);
            csr_src[p0 + pos] = pr.x;
        }
    }
}

// ---------------- P1 = (x @ W1) * dinv  (wave-per-node, grid-stride; R0 body) ----------------
__global__ __launch_bounds__(256) void proj_kernel(const float* __restrict__ A,
                                                   const float* __restrict__ W,
                                                   const float* __restrict__ dinv,
                                                   bf16* __restrict__ P, int N) {
    __shared__ float Wl[4096];
    for (int i = threadIdx.x; i < 4096; i += 256) Wl[i] = W[i];
    __syncthreads();
    int lane = threadIdx.x & 63;
    int wid = (blockIdx.x * 256 + threadIdx.x) >> 6;
    int nwaves = (gridDim.x * 256) >> 6;
    for (int node = wid; node < N; node += nwaves) {
        float a = A[(size_t)node * 64 + lane];
        float acc = 0.f;
#pragma unroll
        for (int k = 0; k < 64; ++k) acc += __shfl(a, k) * Wl[k * 64 + lane];
        P[(size_t)node * 64 + lane] = __float2bfloat16(acc * dinv[node]);
    }
}

// ---- unpack uint4 (8 bf16) and accumulate with weight w ----
__device__ __forceinline__ void acc_bf8(float* acc, uint4 v, float w) {
    unsigned int u[4] = {v.x, v.y, v.z, v.w};
#pragma unroll
    for (int m = 0; m < 4; ++m) {
        float lo = __uint_as_float(u[m] << 16);
        float hi = __uint_as_float(u[m] & 0xffff0000u);
        acc[2 * m]     += w * lo;
        acc[2 * m + 1] += w * hi;
    }
}

// ---- split-wave gather: lanes 0-31 = node A, lanes 32-63 = node B.
//      Each half: 4 r-groups x 8 c-chunks, 2 row-streams (8 edges/iter/node).
//      One load instruction covers 8 full P-rows (4 per node) — same memory
//      efficiency as the R0 body, but TWO dependent chains per instruction
//      stream at ZERO extra register cost (per-lane state unchanged).
//      On return every lane holds acc[0..7] = neighbor-sum for features
//      c*8..c*8+7 of ITS half's node. beg/end are per-half (lockstep-to-max,
//      exec-masked). ----
__device__ __forceinline__ void gather_half(float acc[8],
                                            const bf16* __restrict__ P,
                                            const int* __restrict__ csr_src,
                                            int beg, int end, int r, int c) {
#pragma unroll
    for (int k = 0; k < 8; ++k) acc[k] = 0.f;
    for (int i = beg; i < end; i += 8) {
        int r0 = i + r, r1 = i + 4 + r;
        int ok0 = (r0 < end), ok1 = (r1 < end);
        int s0 = ok0 ? csr_src[r0] : 0;
        int s1 = ok1 ? csr_src[r1] : 0;
        float w0 = ok0 ? 1.f : 0.f;
        float w1 = ok1 ? 1.f : 0.f;
        uint4 v0 = *(const uint4*)(P + (size_t)s0 * 64 + c * 8);
        uint4 v1 = *(const uint4*)(P + (size_t)s1 * 64 + c * 8);
        acc_bf8(acc, v0, w0);
        acc_bf8(acc, v1, w1);
    }
    // butterfly-reduce across the 4 r-groups WITHIN the half (lane bits 3..4)
#pragma unroll
    for (int mask = 8; mask <= 16; mask <<= 1) {
#pragma unroll
        for (int k = 0; k < 8; ++k) acc[k] += __shfl_xor(acc[k], mask);
    }
}

// ---- layer1 aggregate + fused layer2 projection (split-wave: 2 nodes/wave-iter) ----
__global__ __launch_bounds__(256) void agg_proj_kernel(const bf16* __restrict__ P1,
                                                       const int* __restrict__ row_start,
                                                       const int* __restrict__ csr_src,
                                                       const float* __restrict__ dinv,
                                                       const float* __restrict__ b1,
                                                       const float* __restrict__ W2,
                                                       bf16* __restrict__ P2, int N) {
    __shared__ float Wl[4096];
    for (int i = threadIdx.x; i < 4096; i += 256) Wl[i] = W2[i];
    __syncthreads();
    int lane = threadIdx.x & 63;
    int half = lane >> 5;            // 0: node A, 1: node B
    int hl = lane & 31;
    int r = hl >> 3, c = hl & 7;
    float bb[8];
#pragma unroll
    for (int k = 0; k < 8; ++k) bb[k] = b1[c * 8 + k];
    int wid = (blockIdx.x * 256 + threadIdx.x) >> 6;
    int nwaves = (gridDim.x * 256) >> 6;
    int npairs = (N + 1) >> 1;
    for (int p = wid; p < npairs; p += nwaves) {
        int node = 2 * p + half;
        int ok = node < N;
        int nd = ok ? node : N - 1;
        int beg = row_start[nd];
        int end = ok ? row_start[nd + 1] : beg;
        float acc[8];
        gather_half(acc, P1, csr_src, beg, end, r, c);
        // self-loop chunk (added once per lane, after reduction)
        uint4 vs = *(const uint4*)(P1 + (size_t)nd * 64 + c * 8);
        acc_bf8(acc, vs, 1.f);
        float dv = dinv[nd];
        float h[8];
#pragma unroll
        for (int k = 0; k < 8; ++k) h[k] = fmaxf(acc[k] * dv + bb[k], 0.f);
        // fused projection: lane computes features hl and hl+32 of its node.
        // h_j of this half's node lives on lane (j>>3)+half*32, element j&7.
        float a2lo = 0.f, a2hi = 0.f;
#pragma unroll
        for (int j = 0; j < 64; ++j) {
            float hj = __shfl(h[j & 7], (j >> 3) + (half << 5));
            a2lo += hj * Wl[j * 64 + hl];
            a2hi += hj * Wl[j * 64 + hl + 32];
        }
        if (ok) {
            P2[(size_t)node * 64 + hl]      = __float2bfloat16(a2lo * dv);
            P2[(size_t)node * 64 + hl + 32] = __float2bfloat16(a2hi * dv);
        }
    }
}

// ---- layer2 aggregate + fused mean-pool accumulation (split-wave) ----
__global__ __launch_bounds__(256) void agg_pool_kernel(const bf16* __restrict__ P2,
                                                       const int* __restrict__ row_start,
                                                       const int* __restrict__ csr_src,
                                                       const float* __restrict__ dinv,
                                                       const float* __restrict__ b2,
                                                       const int* __restrict__ batch,
                                                       float* __restrict__ out_h,
                                                       float* __restrict__ accum, int N) {
    int lane = threadIdx.x & 63;
    int half = lane >> 5;
    int hl = lane & 31;
    int r = hl >> 3, c = hl & 7;
    float bb[8];
#pragma unroll
    for (int k = 0; k < 8; ++k) bb[k] = b2[c * 8 + k];
    // transpose sources: feature hl comes from lane (hl>>3)+half*32 (c=hl>>3, r=0),
    // feature hl+32 from lane (hl>>3)+4+half*32 (c=(hl>>3)+4). Element index is
    // hl&7 for both ((f>>3)*8 + (f&7) == f).
    int src_lo = (hl >> 3) + (half << 5);
    int src_hi = (hl >> 3) + 4 + (half << 5);
    int wid = (blockIdx.x * 256 + threadIdx.x) >> 6;
    int nwaves = (gridDim.x * 256) >> 6;
    int npairs = (N + 1) >> 1;
    for (int p = wid; p < npairs; p += nwaves) {
        int node = 2 * p + half;
        int ok = node < N;
        int nd = ok ? node : N - 1;
        int beg = row_start[nd];
        int end = ok ? row_start[nd + 1] : beg;
        float acc[8];
        gather_half(acc, P2, csr_src, beg, end, r, c);
        uint4 vs = *(const uint4*)(P2 + (size_t)nd * 64 + c * 8);
        acc_bf8(acc, vs, 1.f);
        float dv = dinv[nd];
        float h[8];
#pragma unroll
        for (int k = 0; k < 8; ++k) h[k] = acc[k] * dv + bb[k];
        // in-register transpose: lane ends up holding features hl and hl+32
        float vlo = 0.f, vhi = 0.f;
#pragma unroll
        for (int k = 0; k < 8; ++k) {
            float tlo = __shfl(h[k], src_lo);
            float thi = __shfl(h[k], src_hi);
            if ((hl & 7) == k) { vlo = tlo; vhi = thi; }
        }
        if (ok) {
            out_h[(size_t)node * 64 + hl]      = vlo;
            out_h[(size_t)node * 64 + hl + 32] = vhi;
            int g = batch[nd];
            g = max(0, min(g, NGRAPH - 1));
            atomicAdd(&accum[g * 64 + hl], vlo);
            atomicAdd(&accum[g * 64 + hl + 32], vhi);
        }
    }
}

// ---------------- finalize pool (divide by count) + classifier head ----------------
__device__ __forceinline__ int lower_bound_dev(const int* a, int n, int key) {
    int lo = 0, hi = n;
    while (lo < hi) {
        int mid = (lo + hi) >> 1;
        if (a[mid] < key) lo = mid + 1; else hi = mid;
    }
    return lo;
}

__global__ __launch_bounds__(64) void final_kernel(const float* __restrict__ accum,
                                                   const int* __restrict__ batch,
                                                   const float* __restrict__ Wc1,
                                                   const float* __restrict__ bc1,
                                                   const float* __restrict__ Wc2,
                                                   const float* __restrict__ bc2,
                                                   float* __restrict__ out_reps,
                                                   float* __restrict__ out_logits, int N) {
    __shared__ float rep[64];
    __shared__ float t[64];
    int g = blockIdx.x;
    int f = threadIdx.x;
    int lo = lower_bound_dev(batch, N, g);
    int hi = lower_bound_dev(batch, N, g + 1);
    float cnt = (float)(hi - lo);
    float r = accum[g * 64 + f] / fmaxf(cnt, 1.f);
    out_reps[g * 64 + f] = r;
    rep[f] = r;
    __syncthreads();
    float acc = bc1[f];
#pragma unroll
    for (int k = 0; k < 64; ++k) acc += rep[k] * Wc1[k * 64 + f];
    t[f] = fmaxf(acc, 0.f);
    __syncthreads();
    if (f < 16) {
        float a2 = bc2[f];
#pragma unroll
        for (int k = 0; k < 64; ++k) a2 += t[k] * Wc2[k * 16 + f];
        out_logits[g * 16 + f] = a2;
    }
}

extern "C" void kernel_launch(void* const* d_in, const int* in_sizes, int n_in,
                              void* d_out, int out_size, void* d_ws, size_t ws_size,
                              hipStream_t stream) {
    const float* x    = (const float*)d_in[0];
    const int*   ei   = (const int*)d_in[1];
    const int*   batch= (const int*)d_in[2];
    const float* W1   = (const float*)d_in[3];
    const float* b1   = (const float*)d_in[4];
    const float* W2   = (const float*)d_in[5];
    const float* b2   = (const float*)d_in[6];
    const float* Wc1  = (const float*)d_in[7];
    const float* bc1  = (const float*)d_in[8];
    const float* Wc2  = (const float*)d_in[9];
    const float* bc2  = (const float*)d_in[10];

    const int N = in_sizes[2];          // 50000
    const int E = in_sizes[1] / 2;      // 800000
    const int nb = (N + 255) >> 8;      // coarse buckets (196 for N=50000)

    // ---- workspace layout (~16.6 MB; pairbuf aliases P2 region) ----
    char* ws = (char*)d_ws;
    size_t off = 0;
    auto alloc = [&](size_t bytes) { void* p = ws + off; off += (bytes + 255) & ~(size_t)255; return p; };
    float* accum      = (float*)alloc((size_t)NGRAPH * 64 * 4);
    int*   bucket_cnt = (int*)  alloc((size_t)MAXNB * 4);
    size_t zero_bytes = off;                       // accum + bucket_cnt start at 0
    int*   bucket_off = (int*)  alloc((size_t)(MAXNB + 1) * 4);
    int*   bucket_cur = (int*)  alloc((size_t)MAXNB * 4);
    float* dinv       = (float*)alloc((size_t)N * 4);
    int*   row_start  = (int*)  alloc((size_t)(N + 1) * 4);
    int*   csr_src    = (int*)  alloc((size_t)E * 4);
    bf16*  P1         = (bf16*) alloc((size_t)N * 64 * 2);
    size_t p2_bytes   = (size_t)N * 64 * 2;
    size_t pair_bytes = (size_t)E * 8;
    void*  p2_region  = alloc(p2_bytes > pair_bytes ? p2_bytes : pair_bytes);
    bf16*  P2         = (bf16*)p2_region;          // live: agg_proj -> agg_pool
    int2*  pairbuf    = (int2*)p2_region;          // live: B3 -> B4 (disjoint lifetime)
    (void)ws_size; (void)n_in; (void)out_size;

    float* out_h      = (float*)d_out;                      // [N,64]
    float* out_reps   = out_h + (size_t)N * 64;             // [128,64]
    float* out_logits = out_reps + (size_t)NGRAPH * 64;     // [128,16]

    const int GS = 2048;                 // grid-stride blocks (8192 waves)

    hipMemsetAsync(d_ws, 0, zero_bytes, stream);
    bucket_count_kernel<<<256, 256, 0, stream>>>(ei, bucket_cnt, E, N, nb);
    bucket_scan_kernel<<<1, 256, 0, stream>>>(bucket_cnt, bucket_off, bucket_cur, nb);
    bucket_scatter_kernel<<<256, 256, 0, stream>>>(ei, bucket_cur, pairbuf, E, N, nb);
    bucket_build_kernel<<<nb, 256, 0, stream>>>(pairbuf, bucket_off, row_start, dinv,
                                                csr_src, E, N, nb);

    proj_kernel<<<GS, 256, 0, stream>>>(x, W1, dinv, P1, N);
    agg_proj_kernel<<<GS, 256, 0, stream>>>(P1, row_start, csr_src, dinv, b1, W2, P2, N);
    agg_pool_kernel<<<GS, 256, 0, stream>>>(P2, row_start, csr_src, dinv, b2, batch,
                                            out_h, accum, N);
    final_kernel<<<NGRAPH, 64, 0, stream>>>(accum, batch, Wc1, bc1, Wc2, bc2,
                                            out_reps, out_logits, N);
}

// Round 10
// 250.238 us; speedup vs baseline: 1.2417x; 1.2417x over previous
//
#include <hip/hip_runtime.h>
#include <hip/hip_bf16.h>

typedef __hip_bfloat16 bf16;

#define NGRAPH 128
#define MAXNB 256      // max coarse buckets (N <= 65536); nb = ceil(N/256)
#define BCAP 8192      // LDS staging capacity per bucket (avg bucket = 4096 edges)

// ---------------- B1: coarse bucket histogram (dst >> 8) ----------------
__global__ __launch_bounds__(256) void bucket_count_kernel(const int* __restrict__ ei,
                                                           int* __restrict__ bucket_cnt,
                                                           int E, int N, int nb) {
    __shared__ int hist[MAXNB];
    for (int i = threadIdx.x; i < nb; i += 256) hist[i] = 0;
    __syncthreads();
    int stride = gridDim.x * 256;
    for (int e = blockIdx.x * 256 + threadIdx.x; e < E; e += stride) {
        int d = ei[E + e];
        d = max(0, min(d, N - 1));
        atomicAdd(&hist[d >> 8], 1);
    }
    __syncthreads();
    for (int i = threadIdx.x; i < nb; i += 256) {
        int c = hist[i];
        if (c) atomicAdd(&bucket_cnt[i], c);
    }
}

// ---------------- B2: scan bucket counts -> bucket_off, init bucket_cur ----------------
__global__ __launch_bounds__(256) void bucket_scan_kernel(const int* __restrict__ bucket_cnt,
                                                          int* __restrict__ bucket_off,
                                                          int* __restrict__ bucket_cur, int nb) {
    __shared__ int tmp[256];
    int tid = threadIdx.x;
    int v = (tid < nb) ? bucket_cnt[tid] : 0;
    tmp[tid] = v;
    __syncthreads();
    for (int off = 1; off < 256; off <<= 1) {
        int t = (tid >= off) ? tmp[tid - off] : 0;
        __syncthreads();
        tmp[tid] += t;
        __syncthreads();
    }
    int excl = tmp[tid] - v;
    if (tid < nb) { bucket_off[tid] = excl; bucket_cur[tid] = excl; }
    if (tid == nb - 1) bucket_off[nb] = excl + v;   // = E
}

// ---------------- B3: scatter edges into bucket-contiguous packed buffer ----------------
// Entry packs (src << 8) | (dst & 255): src needs <=17 bits (N <= 65536), the
// bucket-local dst 8 bits — halves the scatter-write payload vs int2 pairs.
__global__ __launch_bounds__(256) void bucket_scatter_kernel(const int* __restrict__ ei,
                                                             int* __restrict__ bucket_cur,
                                                             int* __restrict__ pairbuf,
                                                             int E, int N, int nb) {
    __shared__ int hist[MAXNB];
    int nwg = gridDim.x;
    int chunk = (E + nwg - 1) / nwg;
    int e0 = blockIdx.x * chunk;
    int e1 = e0 + chunk; if (e1 > E) e1 = E;
    if (e0 >= e1) return;
    for (int i = threadIdx.x; i < nb; i += 256) hist[i] = 0;
    __syncthreads();
    // pass 1: count chunk edges per bucket
    for (int e = e0 + threadIdx.x; e < e1; e += 256) {
        int d = ei[E + e];
        d = max(0, min(d, N - 1));
        atomicAdd(&hist[d >> 8], 1);
    }
    __syncthreads();
    // reserve global ranges: hist[i] becomes this WG's running cursor
    for (int i = threadIdx.x; i < nb; i += 256) {
        int c = hist[i];
        hist[i] = c ? atomicAdd(&bucket_cur[i], c) : 0;
    }
    __syncthreads();
    // pass 2: append packed (src, dst_local) entries
    for (int e = e0 + threadIdx.x; e < e1; e += 256) {
        int s = ei[e];     s = max(0, min(s, N - 1));
        int d = ei[E + e]; d = max(0, min(d, N - 1));
        int pos = atomicAdd(&hist[d >> 8], 1);
        pairbuf[pos] = (s << 8) | (d & 255);
    }
}

// ---------------- B4: per-bucket degree + dinv + row_start + counting sort ----------------
__global__ __launch_bounds__(256) void bucket_build_kernel(const int* __restrict__ pairbuf,
                                                           const int* __restrict__ bucket_off,
                                                           int* __restrict__ row_start,
                                                           float* __restrict__ dinv,
                                                           int* __restrict__ csr_src,
                                                           int E, int N, int nb) {
    __shared__ int deg_l[256];
    __shared__ int cur_l[256];
    __shared__ int stage[BCAP];
    int b = blockIdx.x;              // grid = nb
    int node0 = b << 8;
    int nn = N - node0; if (nn > 256) nn = 256;
    int p0 = bucket_off[b], p1 = bucket_off[b + 1];
    int ne = p1 - p0;
    int tid = threadIdx.x;
    deg_l[tid] = 0;
    __syncthreads();
    for (int i = p0 + tid; i < p1; i += 256) {
        int dl = pairbuf[i] & 255;   // bucket-local dst
        atomicAdd(&deg_l[dl], 1);
    }
    __syncthreads();
    int v = deg_l[tid];
    for (int off = 1; off < 256; off <<= 1) {
        int t = (tid >= off) ? deg_l[tid - off] : 0;
        __syncthreads();
        deg_l[tid] += t;
        __syncthreads();
    }
    int excl = deg_l[tid] - v;
    if (tid < nn) {
        row_start[node0 + tid] = p0 + excl;
        dinv[node0 + tid] = rsqrtf((float)(v + 1));   // +1 self loop
    }
    if (b == nb - 1 && tid == nn - 1) row_start[N] = p0 + excl + v;   // = E
    cur_l[tid] = excl;
    __syncthreads();
    if (ne <= BCAP) {
        for (int i = p0 + tid; i < p1; i += 256) {
            int pr = pairbuf[i];
            int pos = atomicAdd(&cur_l[pr & 255], 1);
            stage[pos] = pr >> 8;
        }
        __syncthreads();
        for (int i = tid; i < ne; i += 256) csr_src[p0 + i] = stage[i];
    } else {
        // statistically-never fallback (bucket > BCAP edges): direct scatter
        for (int i = p0 + tid; i < p1; i += 256) {
            int pr = pairbuf[i];
            int pos = atomicAdd(&cur_l[pr & 255], 1);
            csr_src[p0 + pos] = pr >> 8;
        }
    }
}

// ---------------- P1 = (x @ W1) * dinv  (wave-per-node, grid-stride; R0 body) ----------------
__global__ __launch_bounds__(256) void proj_kernel(const float* __restrict__ A,
                                                   const float* __restrict__ W,
                                                   const float* __restrict__ dinv,
                                                   bf16* __restrict__ P, int N) {
    __shared__ float Wl[4096];
    for (int i = threadIdx.x; i < 4096; i += 256) Wl[i] = W[i];
    __syncthreads();
    int lane = threadIdx.x & 63;
    int wid = (blockIdx.x * 256 + threadIdx.x) >> 6;
    int nwaves = (gridDim.x * 256) >> 6;
    for (int node = wid; node < N; node += nwaves) {
        float a = A[(size_t)node * 64 + lane];
        float acc = 0.f;
#pragma unroll
        for (int k = 0; k < 64; ++k) acc += __shfl(a, k) * Wl[k * 64 + lane];
        P[(size_t)node * 64 + lane] = __float2bfloat16(acc * dinv[node]);
    }
}

// ---- unpack uint4 (8 bf16) and accumulate with weight w ----
__device__ __forceinline__ void acc_bf8(float* acc, uint4 v, float w) {
    unsigned int u[4] = {v.x, v.y, v.z, v.w};
#pragma unroll
    for (int m = 0; m < 4; ++m) {
        float lo = __uint_as_float(u[m] << 16);
        float hi = __uint_as_float(u[m] & 0xffff0000u);
        acc[2 * m]     += w * lo;
        acc[2 * m + 1] += w * hi;
    }
}

// ---- wide gather: 8 rows per load instruction, unroll x2 (16 rows in flight).
//      EXACT R0 body (proven 64-VGPR dual-stream codegen). ----
__device__ __forceinline__ void gather_sum8(float* acc,
                                            const bf16* __restrict__ P,
                                            const int* __restrict__ csr_src,
                                            int beg, int end, int r, int c) {
#pragma unroll
    for (int k = 0; k < 8; ++k) acc[k] = 0.f;
    for (int i = beg; i < end; i += 16) {
        int r0 = i + r, r1 = i + 8 + r;
        int ok0 = (r0 < end), ok1 = (r1 < end);
        int s0 = ok0 ? csr_src[r0] : 0;
        int s1 = ok1 ? csr_src[r1] : 0;
        float w0 = ok0 ? 1.f : 0.f;
        float w1 = ok1 ? 1.f : 0.f;
        uint4 v0 = *(const uint4*)(P + (size_t)s0 * 64 + c * 8);
        uint4 v1 = *(const uint4*)(P + (size_t)s1 * 64 + c * 8);
        acc_bf8(acc, v0, w0);
        acc_bf8(acc, v1, w1);
    }
    // butterfly-reduce across the 8 r-groups (lane bits 3..5)
#pragma unroll
    for (int mask = 8; mask <= 32; mask <<= 1) {
#pragma unroll
        for (int k = 0; k < 8; ++k) acc[k] += __shfl_xor(acc[k], mask);
    }
}

// ---- layer1 aggregate + fused layer2 projection (R0 body, contiguous node range) ----
__global__ __launch_bounds__(256) void agg_proj_kernel(const bf16* __restrict__ P1,
                                                       const int* __restrict__ row_start,
                                                       const int* __restrict__ csr_src,
                                                       const float* __restrict__ dinv,
                                                       const float* __restrict__ b1,
                                                       const float* __restrict__ W2,
                                                       bf16* __restrict__ P2, int N) {
    __shared__ float Wl[4096];
    for (int i = threadIdx.x; i < 4096; i += 256) Wl[i] = W2[i];
    __syncthreads();
    int lane = threadIdx.x & 63;
    int r = lane >> 3, c = lane & 7;
    float bb[8];
#pragma unroll
    for (int k = 0; k < 8; ++k) bb[k] = b1[c * 8 + k];
    int wid = (blockIdx.x * 256 + threadIdx.x) >> 6;
    int nwaves = (gridDim.x * 256) >> 6;
    int cpn = (N + nwaves - 1) / nwaves;         // contiguous nodes per wave
    int node0 = wid * cpn;
    int node1 = node0 + cpn; if (node1 > N) node1 = N;
    for (int node = node0; node < node1; ++node) {
        float acc[8];
        gather_sum8(acc, P1, csr_src, row_start[node], row_start[node + 1], r, c);
        // self-loop chunk (added once per lane, after reduction)
        uint4 vs = *(const uint4*)(P1 + (size_t)node * 64 + c * 8);
        acc_bf8(acc, vs, 1.f);
        float dv = dinv[node];
        float h[8];
#pragma unroll
        for (int k = 0; k < 8; ++k) h[k] = fmaxf(acc[k] * dv + bb[k], 0.f);
        // fused projection: P2[node][lane] = (h1 @ W2)[lane] * dinv
        float acc2 = 0.f;
#pragma unroll
        for (int c2 = 0; c2 < 8; ++c2) {
#pragma unroll
            for (int j = 0; j < 8; ++j) {
                acc2 += __shfl(h[j], c2) * Wl[(c2 * 8 + j) * 64 + lane];
            }
        }
        P2[(size_t)node * 64 + lane] = __float2bfloat16(acc2 * dv);
    }
}

// ---- layer2 aggregate + fused mean-pool accumulation (R0 body, contiguous range) ----
__global__ __launch_bounds__(256) void agg_pool_kernel(const bf16* __restrict__ P2,
                                                       const int* __restrict__ row_start,
                                                       const int* __restrict__ csr_src,
                                                       const float* __restrict__ dinv,
                                                       const float* __restrict__ b2,
                                                       const int* __restrict__ batch,
                                                       float* __restrict__ out_h,
                                                       float* __restrict__ accum, int N) {
    int lane = threadIdx.x & 63;
    int r = lane >> 3, c = lane & 7;
    float bb[8];
#pragma unroll
    for (int k = 0; k < 8; ++k) bb[k] = b2[c * 8 + k];
    // transpose source lane: holds c' = lane>>3, i.e. features (lane>>3)*8+k
    int src = ((lane & 7) << 3) | (lane >> 3);
    int wid = (blockIdx.x * 256 + threadIdx.x) >> 6;
    int nwaves = (gridDim.x * 256) >> 6;
    int cpn = (N + nwaves - 1) / nwaves;
    int node0 = wid * cpn;
    int node1 = node0 + cpn; if (node1 > N) node1 = N;
    for (int node = node0; node < node1; ++node) {
        float acc[8];
        gather_sum8(acc, P2, csr_src, row_start[node], row_start[node + 1], r, c);
        uint4 vs = *(const uint4*)(P2 + (size_t)node * 64 + c * 8);
        acc_bf8(acc, vs, 1.f);
        float dv = dinv[node];
        float h[8];
#pragma unroll
        for (int k = 0; k < 8; ++k) h[k] = acc[k] * dv + bb[k];
        // in-register transpose: lane l ends up holding feature l
        float val = 0.f;
#pragma unroll
        for (int k = 0; k < 8; ++k) {
            float t = __shfl(h[k], src);
            val = ((lane & 7) == k) ? t : val;
        }
        // coalesced wave-wide store (256 B contiguous) + ONE wave-wide atomic
        out_h[(size_t)node * 64 + lane] = val;
        int g = batch[node];
        g = max(0, min(g, NGRAPH - 1));
        atomicAdd(&accum[g * 64 + lane], val);
    }
}

// ---------------- finalize pool (divide by count) + classifier head ----------------
__device__ __forceinline__ int lower_bound_dev(const int* a, int n, int key) {
    int lo = 0, hi = n;
    while (lo < hi) {
        int mid = (lo + hi) >> 1;
        if (a[mid] < key) lo = mid + 1; else hi = mid;
    }
    return lo;
}

__global__ __launch_bounds__(64) void final_kernel(const float* __restrict__ accum,
                                                   const int* __restrict__ batch,
                                                   const float* __restrict__ Wc1,
                                                   const float* __restrict__ bc1,
                                                   const float* __restrict__ Wc2,
                                                   const float* __restrict__ bc2,
                                                   float* __restrict__ out_reps,
                                                   float* __restrict__ out_logits, int N) {
    __shared__ float rep[64];
    __shared__ float t[64];
    int g = blockIdx.x;
    int f = threadIdx.x;
    int lo = lower_bound_dev(batch, N, g);
    int hi = lower_bound_dev(batch, N, g + 1);
    float cnt = (float)(hi - lo);
    float r = accum[g * 64 + f] / fmaxf(cnt, 1.f);
    out_reps[g * 64 + f] = r;
    rep[f] = r;
    __syncthreads();
    float acc = bc1[f];
#pragma unroll
    for (int k = 0; k < 64; ++k) acc += rep[k] * Wc1[k * 64 + f];
    t[f] = fmaxf(acc, 0.f);
    __syncthreads();
    if (f < 16) {
        float a2 = bc2[f];
#pragma unroll
        for (int k = 0; k < 64; ++k) a2 += t[k] * Wc2[k * 16 + f];
        out_logits[g * 16 + f] = a2;
    }
}

extern "C" void kernel_launch(void* const* d_in, const int* in_sizes, int n_in,
                              void* d_out, int out_size, void* d_ws, size_t ws_size,
                              hipStream_t stream) {
    const float* x    = (const float*)d_in[0];
    const int*   ei   = (const int*)d_in[1];
    const int*   batch= (const int*)d_in[2];
    const float* W1   = (const float*)d_in[3];
    const float* b1   = (const float*)d_in[4];
    const float* W2   = (const float*)d_in[5];
    const float* b2   = (const float*)d_in[6];
    const float* Wc1  = (const float*)d_in[7];
    const float* bc1  = (const float*)d_in[8];
    const float* Wc2  = (const float*)d_in[9];
    const float* bc2  = (const float*)d_in[10];

    const int N = in_sizes[2];          // 50000
    const int E = in_sizes[1] / 2;      // 800000
    const int nb = (N + 255) >> 8;      // coarse buckets (196 for N=50000)

    // ---- workspace layout (~16.6 MB; pairbuf aliases P2 region) ----
    char* ws = (char*)d_ws;
    size_t off = 0;
    auto alloc = [&](size_t bytes) { void* p = ws + off; off += (bytes + 255) & ~(size_t)255; return p; };
    float* accum      = (float*)alloc((size_t)NGRAPH * 64 * 4);
    int*   bucket_cnt = (int*)  alloc((size_t)MAXNB * 4);
    size_t zero_bytes = off;                       // accum + bucket_cnt start at 0
    int*   bucket_off = (int*)  alloc((size_t)(MAXNB + 1) * 4);
    int*   bucket_cur = (int*)  alloc((size_t)MAXNB * 4);
    float* dinv       = (float*)alloc((size_t)N * 4);
    int*   row_start  = (int*)  alloc((size_t)(N + 1) * 4);
    int*   csr_src    = (int*)  alloc((size_t)E * 4);
    bf16*  P1         = (bf16*) alloc((size_t)N * 64 * 2);
    size_t p2_bytes   = (size_t)N * 64 * 2;
    size_t pair_bytes = (size_t)E * 4;             // packed entries (int)
    void*  p2_region  = alloc(p2_bytes > pair_bytes ? p2_bytes : pair_bytes);
    bf16*  P2         = (bf16*)p2_region;          // live: agg_proj -> agg_pool
    int*   pairbuf    = (int*)p2_region;           // live: B3 -> B4 (disjoint lifetime)
    (void)ws_size; (void)n_in; (void)out_size;

    float* out_h      = (float*)d_out;                      // [N,64]
    float* out_reps   = out_h + (size_t)N * 64;             // [128,64]
    float* out_logits = out_reps + (size_t)NGRAPH * 64;     // [128,16]

    const int GS = 2048;                 // grid-stride blocks (8192 waves)

    hipMemsetAsync(d_ws, 0, zero_bytes, stream);
    bucket_count_kernel<<<256, 256, 0, stream>>>(ei, bucket_cnt, E, N, nb);
    bucket_scan_kernel<<<1, 256, 0, stream>>>(bucket_cnt, bucket_off, bucket_cur, nb);
    bucket_scatter_kernel<<<256, 256, 0, stream>>>(ei, bucket_cur, pairbuf, E, N, nb);
    bucket_build_kernel<<<nb, 256, 0, stream>>>(pairbuf, bucket_off, row_start, dinv,
                                                csr_src, E, N, nb);

    proj_kernel<<<GS, 256, 0, stream>>>(x, W1, dinv, P1, N);
    agg_proj_kernel<<<GS, 256, 0, stream>>>(P1, row_start, csr_src, dinv, b1, W2, P2, N);
    agg_pool_kernel<<<GS, 256, 0, stream>>>(P2, row_start, csr_src, dinv, b2, batch,
                                            out_h, accum, N);
    final_kernel<<<NGRAPH, 64, 0, stream>>>(accum, batch, Wc1, bc1, Wc2, bc2,
                                            out_reps, out_logits, N);
}

// Round 11
// 247.198 us; speedup vs baseline: 1.2569x; 1.0123x over previous
//
#include <hip/hip_runtime.h>
#include <hip/hip_bf16.h>

typedef __hip_bfloat16 bf16;

#define NGRAPH 128
#define MAXNB 256      // max coarse buckets (N <= 65536); nb = ceil(N/256)
#define BCAP 8192      // LDS staging capacity per bucket (avg bucket = 4096 edges)

// ---------------- fused: B1 bucket histogram (blocks [0,256)) + P1 projection ----
// proj no longer needs dinv (P1 stores UNNORMALIZED x@W1; dinv[src] is applied
// as the gather weight in agg_proj) -> proj is graph-independent and overlaps
// the histogram in one launch on disjoint block ranges (R6-proven pattern).
__global__ __launch_bounds__(256) void projB1_kernel(const int* __restrict__ ei,
                                                     int* __restrict__ bucket_cnt,
                                                     const float* __restrict__ A,
                                                     const float* __restrict__ W,
                                                     bf16* __restrict__ P,
                                                     int E, int N, int nb) {
    __shared__ float Wl[4096];
    int* hist = (int*)Wl;
    if ((int)blockIdx.x < 256) {
        // ---- B1: coarse bucket histogram (dst >> 8), LDS-aggregated ----
        for (int i = threadIdx.x; i < nb; i += 256) hist[i] = 0;
        __syncthreads();
        int stride = 256 * 256;
        for (int e = blockIdx.x * 256 + threadIdx.x; e < E; e += stride) {
            int d = ei[E + e];
            d = max(0, min(d, N - 1));
            atomicAdd(&hist[d >> 8], 1);
        }
        __syncthreads();
        for (int i = threadIdx.x; i < nb; i += 256) {
            int c = hist[i];
            if (c) atomicAdd(&bucket_cnt[i], c);
        }
        return;
    }
    // ---- proj: P1 = x @ W1 (wave-per-node, grid-stride; R0 body, NO dinv) ----
    for (int i = threadIdx.x; i < 4096; i += 256) Wl[i] = W[i];
    __syncthreads();
    int lane = threadIdx.x & 63;
    int wid = (((int)blockIdx.x - 256) * 256 + threadIdx.x) >> 6;
    int nwaves = (((int)gridDim.x - 256) * 256) >> 6;
    for (int node = wid; node < N; node += nwaves) {
        float a = A[(size_t)node * 64 + lane];
        float acc = 0.f;
#pragma unroll
        for (int k = 0; k < 64; ++k) acc += __shfl(a, k) * Wl[k * 64 + lane];
        P[(size_t)node * 64 + lane] = __float2bfloat16(acc);
    }
}

// ---------------- B3: scatter edges into bucket-contiguous packed buffer ----------------
// Local scan of bucket_cnt replaces the old B2 kernel; bucket_cur_rel is a
// RELATIVE cursor (memset-zeroed), global base = local exclusive scan.
// Entry packs (src << 8) | (dst & 255).
__global__ __launch_bounds__(256) void bucket_scatter_kernel(const int* __restrict__ ei,
                                                             const int* __restrict__ bucket_cnt,
                                                             int* __restrict__ bucket_cur_rel,
                                                             int* __restrict__ pairbuf,
                                                             int E, int N, int nb) {
    __shared__ int boff_l[MAXNB];
    __shared__ int hist[MAXNB];
    int tid = threadIdx.x;
    // local exclusive scan of bucket_cnt -> boff_l
    int v = (tid < nb) ? bucket_cnt[tid] : 0;
    boff_l[tid] = v;
    __syncthreads();
    for (int off = 1; off < 256; off <<= 1) {
        int t = (tid >= off) ? boff_l[tid - off] : 0;
        __syncthreads();
        boff_l[tid] += t;
        __syncthreads();
    }
    boff_l[tid] -= v;                      // exclusive
    int nwg = gridDim.x;
    int chunk = (E + nwg - 1) / nwg;
    int e0 = blockIdx.x * chunk;
    int e1 = e0 + chunk; if (e1 > E) e1 = E;
    for (int i = tid; i < nb; i += 256) hist[i] = 0;
    __syncthreads();
    if (e0 >= e1) return;
    // pass 1: count chunk edges per bucket
    for (int e = e0 + tid; e < e1; e += 256) {
        int d = ei[E + e];
        d = max(0, min(d, N - 1));
        atomicAdd(&hist[d >> 8], 1);
    }
    __syncthreads();
    // reserve global ranges: hist[i] becomes this WG's running absolute cursor
    for (int i = tid; i < nb; i += 256) {
        int c = hist[i];
        hist[i] = c ? (boff_l[i] + atomicAdd(&bucket_cur_rel[i], c)) : 0;
    }
    __syncthreads();
    // pass 2: append packed (src, dst_local) entries
    for (int e = e0 + tid; e < e1; e += 256) {
        int s = ei[e];     s = max(0, min(s, N - 1));
        int d = ei[E + e]; d = max(0, min(d, N - 1));
        int pos = atomicAdd(&hist[d >> 8], 1);
        pairbuf[pos] = (s << 8) | (d & 255);
    }
}

// ---------------- B4: per-bucket degree + dinv + row_start + counting sort ----------------
// p0/p1 come from a local scan of bucket_cnt (B2 eliminated).
__global__ __launch_bounds__(256) void bucket_build_kernel(const int* __restrict__ pairbuf,
                                                           const int* __restrict__ bucket_cnt,
                                                           int* __restrict__ row_start,
                                                           float* __restrict__ dinv,
                                                           int* __restrict__ csr_src,
                                                           int E, int N, int nb) {
    __shared__ int deg_l[256];
    __shared__ int cur_l[256];
    __shared__ int stage[BCAP];
    int b = blockIdx.x;              // grid = nb
    int node0 = b << 8;
    int nn = N - node0; if (nn > 256) nn = 256;
    int tid = threadIdx.x;
    // local inclusive scan of bucket_cnt in cur_l -> p0/p1 for THIS bucket
    int cv = (tid < nb) ? bucket_cnt[tid] : 0;
    cur_l[tid] = cv;
    __syncthreads();
    for (int off = 1; off < 256; off <<= 1) {
        int t = (tid >= off) ? cur_l[tid - off] : 0;
        __syncthreads();
        cur_l[tid] += t;
        __syncthreads();
    }
    int p1 = cur_l[b];
    int p0 = p1 - ((b < nb) ? bucket_cnt[b] : 0);
    int ne = p1 - p0;
    __syncthreads();
    deg_l[tid] = 0;
    __syncthreads();
    for (int i = p0 + tid; i < p1; i += 256) {
        int dl = pairbuf[i] & 255;   // bucket-local dst
        atomicAdd(&deg_l[dl], 1);
    }
    __syncthreads();
    int v = deg_l[tid];
    for (int off = 1; off < 256; off <<= 1) {
        int t = (tid >= off) ? deg_l[tid - off] : 0;
        __syncthreads();
        deg_l[tid] += t;
        __syncthreads();
    }
    int excl = deg_l[tid] - v;
    if (tid < nn) {
        row_start[node0 + tid] = p0 + excl;
        dinv[node0 + tid] = rsqrtf((float)(v + 1));   // +1 self loop
    }
    if (b == nb - 1 && tid == 0) row_start[N] = p1;   // = E
    cur_l[tid] = excl;
    __syncthreads();
    if (ne <= BCAP) {
        for (int i = p0 + tid; i < p1; i += 256) {
            int pr = pairbuf[i];
            int pos = atomicAdd(&cur_l[pr & 255], 1);
            stage[pos] = pr >> 8;
        }
        __syncthreads();
        for (int i = tid; i < ne; i += 256) csr_src[p0 + i] = stage[i];
    } else {
        // statistically-never fallback (bucket > BCAP edges): direct scatter
        for (int i = p0 + tid; i < p1; i += 256) {
            int pr = pairbuf[i];
            int pos = atomicAdd(&cur_l[pr & 255], 1);
            csr_src[p0 + pos] = pr >> 8;
        }
    }
}

// ---- unpack uint4 (8 bf16) and accumulate with weight w ----
__device__ __forceinline__ void acc_bf8(float* acc, uint4 v, float w) {
    unsigned int u[4] = {v.x, v.y, v.z, v.w};
#pragma unroll
    for (int m = 0; m < 4; ++m) {
        float lo = __uint_as_float(u[m] << 16);
        float hi = __uint_as_float(u[m] & 0xffff0000u);
        acc[2 * m]     += w * lo;
        acc[2 * m + 1] += w * hi;
    }
}

// ---- wide gather with per-src dinv weight (P rows are UNNORMALIZED).
//      Same load pattern as the proven R0 body: 2 uint4 row-streams in flight;
//      w0/w1 were cndmask-materialized VGPRs before and are now dinv loads into
//      the same registers (dinv is 200 KB, L2-resident; load is independent of
//      the P-row load and overlaps it). ----
__device__ __forceinline__ void gather_sum8_w(float* acc,
                                              const bf16* __restrict__ P,
                                              const int* __restrict__ csr_src,
                                              const float* __restrict__ dinv,
                                              int beg, int end, int r, int c) {
#pragma unroll
    for (int k = 0; k < 8; ++k) acc[k] = 0.f;
    for (int i = beg; i < end; i += 16) {
        int r0 = i + r, r1 = i + 8 + r;
        int ok0 = (r0 < end), ok1 = (r1 < end);
        int s0 = ok0 ? csr_src[r0] : 0;
        int s1 = ok1 ? csr_src[r1] : 0;
        float w0 = ok0 ? dinv[s0] : 0.f;
        float w1 = ok1 ? dinv[s1] : 0.f;
        uint4 v0 = *(const uint4*)(P + (size_t)s0 * 64 + c * 8);
        uint4 v1 = *(const uint4*)(P + (size_t)s1 * 64 + c * 8);
        acc_bf8(acc, v0, w0);
        acc_bf8(acc, v1, w1);
    }
    // butterfly-reduce across the 8 r-groups (lane bits 3..5)
#pragma unroll
    for (int mask = 8; mask <= 32; mask <<= 1) {
#pragma unroll
        for (int k = 0; k < 8; ++k) acc[k] += __shfl_xor(acc[k], mask);
    }
}

// ---- plain wide gather (w=1): EXACT R0 body, used by agg_pool (P2 is baked) ----
__device__ __forceinline__ void gather_sum8(float* acc,
                                            const bf16* __restrict__ P,
                                            const int* __restrict__ csr_src,
                                            int beg, int end, int r, int c) {
#pragma unroll
    for (int k = 0; k < 8; ++k) acc[k] = 0.f;
    for (int i = beg; i < end; i += 16) {
        int r0 = i + r, r1 = i + 8 + r;
        int ok0 = (r0 < end), ok1 = (r1 < end);
        int s0 = ok0 ? csr_src[r0] : 0;
        int s1 = ok1 ? csr_src[r1] : 0;
        float w0 = ok0 ? 1.f : 0.f;
        float w1 = ok1 ? 1.f : 0.f;
        uint4 v0 = *(const uint4*)(P + (size_t)s0 * 64 + c * 8);
        uint4 v1 = *(const uint4*)(P + (size_t)s1 * 64 + c * 8);
        acc_bf8(acc, v0, w0);
        acc_bf8(acc, v1, w1);
    }
#pragma unroll
    for (int mask = 8; mask <= 32; mask <<= 1) {
#pragma unroll
        for (int k = 0; k < 8; ++k) acc[k] += __shfl_xor(acc[k], mask);
    }
}

// ---- layer1 aggregate + fused layer2 projection (dinv-weighted gather).
//      Bias lives in LDS (frees 8 VGPRs to compensate the w0/w1 loads and keep
//      the kernel inside the <=64-VGPR occupancy bucket). ----
__global__ __launch_bounds__(256) void agg_proj_kernel(const bf16* __restrict__ P1,
                                                       const int* __restrict__ row_start,
                                                       const int* __restrict__ csr_src,
                                                       const float* __restrict__ dinv,
                                                       const float* __restrict__ b1,
                                                       const float* __restrict__ W2,
                                                       bf16* __restrict__ P2, int N) {
    __shared__ float Wl[4096];
    __shared__ float bl[64];
    for (int i = threadIdx.x; i < 4096; i += 256) Wl[i] = W2[i];
    if (threadIdx.x < 64) bl[threadIdx.x] = b1[threadIdx.x];
    __syncthreads();
    int lane = threadIdx.x & 63;
    int r = lane >> 3, c = lane & 7;
    int wid = (blockIdx.x * 256 + threadIdx.x) >> 6;
    int nwaves = (gridDim.x * 256) >> 6;
    int cpn = (N + nwaves - 1) / nwaves;         // contiguous nodes per wave
    int node0 = wid * cpn;
    int node1 = node0 + cpn; if (node1 > N) node1 = N;
    for (int node = node0; node < node1; ++node) {
        float acc[8];
        gather_sum8_w(acc, P1, csr_src, dinv, row_start[node], row_start[node + 1], r, c);
        float dv = dinv[node];
        // self-loop chunk, weighted by dinv[node] (P1 is unnormalized)
        uint4 vs = *(const uint4*)(P1 + (size_t)node * 64 + c * 8);
        acc_bf8(acc, vs, dv);
        float h[8];
#pragma unroll
        for (int k = 0; k < 8; ++k) h[k] = fmaxf(acc[k] * dv + bl[c * 8 + k], 0.f);
        // fused projection: P2[node][lane] = (h1 @ W2)[lane] * dinv  (P2 stays baked)
        float acc2 = 0.f;
#pragma unroll
        for (int c2 = 0; c2 < 8; ++c2) {
#pragma unroll
            for (int j = 0; j < 8; ++j) {
                acc2 += __shfl(h[j], c2) * Wl[(c2 * 8 + j) * 64 + lane];
            }
        }
        P2[(size_t)node * 64 + lane] = __float2bfloat16(acc2 * dv);
    }
}

// ---- layer2 aggregate + fused mean-pool accumulation (R0 body, contiguous range) ----
__global__ __launch_bounds__(256) void agg_pool_kernel(const bf16* __restrict__ P2,
                                                       const int* __restrict__ row_start,
                                                       const int* __restrict__ csr_src,
                                                       const float* __restrict__ dinv,
                                                       const float* __restrict__ b2,
                                                       const int* __restrict__ batch,
                                                       float* __restrict__ out_h,
                                                       float* __restrict__ accum, int N) {
    int lane = threadIdx.x & 63;
    int r = lane >> 3, c = lane & 7;
    float bb[8];
#pragma unroll
    for (int k = 0; k < 8; ++k) bb[k] = b2[c * 8 + k];
    // transpose source lane: holds c' = lane>>3, i.e. features (lane>>3)*8+k
    int src = ((lane & 7) << 3) | (lane >> 3);
    int wid = (blockIdx.x * 256 + threadIdx.x) >> 6;
    int nwaves = (gridDim.x * 256) >> 6;
    int cpn = (N + nwaves - 1) / nwaves;
    int node0 = wid * cpn;
    int node1 = node0 + cpn; if (node1 > N) node1 = N;
    for (int node = node0; node < node1; ++node) {
        float acc[8];
        gather_sum8(acc, P2, csr_src, row_start[node], row_start[node + 1], r, c);
        uint4 vs = *(const uint4*)(P2 + (size_t)node * 64 + c * 8);
        acc_bf8(acc, vs, 1.f);
        float dv = dinv[node];
        float h[8];
#pragma unroll
        for (int k = 0; k < 8; ++k) h[k] = acc[k] * dv + bb[k];
        // in-register transpose: lane l ends up holding feature l
        float val = 0.f;
#pragma unroll
        for (int k = 0; k < 8; ++k) {
            float t = __shfl(h[k], src);
            val = ((lane & 7) == k) ? t : val;
        }
        // coalesced wave-wide store (256 B contiguous) + ONE wave-wide atomic
        out_h[(size_t)node * 64 + lane] = val;
        int g = batch[node];
        g = max(0, min(g, NGRAPH - 1));
        atomicAdd(&accum[g * 64 + lane], val);
    }
}

// ---------------- finalize pool (divide by count) + classifier head ----------------
__device__ __forceinline__ int lower_bound_dev(const int* a, int n, int key) {
    int lo = 0, hi = n;
    while (lo < hi) {
        int mid = (lo + hi) >> 1;
        if (a[mid] < key) lo = mid + 1; else hi = mid;
    }
    return lo;
}

__global__ __launch_bounds__(64) void final_kernel(const float* __restrict__ accum,
                                                   const int* __restrict__ batch,
                                                   const float* __restrict__ Wc1,
                                                   const float* __restrict__ bc1,
                                                   const float* __restrict__ Wc2,
                                                   const float* __restrict__ bc2,
                                                   float* __restrict__ out_reps,
                                                   float* __restrict__ out_logits, int N) {
    __shared__ float rep[64];
    __shared__ float t[64];
    int g = blockIdx.x;
    int f = threadIdx.x;
    int lo = lower_bound_dev(batch, N, g);
    int hi = lower_bound_dev(batch, N, g + 1);
    float cnt = (float)(hi - lo);
    float r = accum[g * 64 + f] / fmaxf(cnt, 1.f);
    out_reps[g * 64 + f] = r;
    rep[f] = r;
    __syncthreads();
    float acc = bc1[f];
#pragma unroll
    for (int k = 0; k < 64; ++k) acc += rep[k] * Wc1[k * 64 + f];
    t[f] = fmaxf(acc, 0.f);
    __syncthreads();
    if (f < 16) {
        float a2 = bc2[f];
#pragma unroll
        for (int k = 0; k < 64; ++k) a2 += t[k] * Wc2[k * 16 + f];
        out_logits[g * 16 + f] = a2;
    }
}

extern "C" void kernel_launch(void* const* d_in, const int* in_sizes, int n_in,
                              void* d_out, int out_size, void* d_ws, size_t ws_size,
                              hipStream_t stream) {
    const float* x    = (const float*)d_in[0];
    const int*   ei   = (const int*)d_in[1];
    const int*   batch= (const int*)d_in[2];
    const float* W1   = (const float*)d_in[3];
    const float* b1   = (const float*)d_in[4];
    const float* W2   = (const float*)d_in[5];
    const float* b2   = (const float*)d_in[6];
    const float* Wc1  = (const float*)d_in[7];
    const float* bc1  = (const float*)d_in[8];
    const float* Wc2  = (const float*)d_in[9];
    const float* bc2  = (const float*)d_in[10];

    const int N = in_sizes[2];          // 50000
    const int E = in_sizes[1] / 2;      // 800000
    const int nb = (N + 255) >> 8;      // coarse buckets (196 for N=50000)

    // ---- workspace layout (~16.6 MB; pairbuf aliases P2 region) ----
    char* ws = (char*)d_ws;
    size_t off = 0;
    auto alloc = [&](size_t bytes) { void* p = ws + off; off += (bytes + 255) & ~(size_t)255; return p; };
    float* accum       = (float*)alloc((size_t)NGRAPH * 64 * 4);
    int*   bucket_cnt  = (int*)  alloc((size_t)MAXNB * 4);
    int*   bucket_cur  = (int*)  alloc((size_t)MAXNB * 4);   // RELATIVE cursor
    size_t zero_bytes  = off;                  // accum + bucket_cnt + bucket_cur at 0
    float* dinv        = (float*)alloc((size_t)N * 4);
    int*   row_start   = (int*)  alloc((size_t)(N + 1) * 4);
    int*   csr_src     = (int*)  alloc((size_t)E * 4);
    bf16*  P1          = (bf16*) alloc((size_t)N * 64 * 2);
    size_t p2_bytes    = (size_t)N * 64 * 2;
    size_t pair_bytes  = (size_t)E * 4;        // packed entries (int)
    void*  p2_region   = alloc(p2_bytes > pair_bytes ? p2_bytes : pair_bytes);
    bf16*  P2          = (bf16*)p2_region;     // live: agg_proj -> agg_pool
    int*   pairbuf     = (int*)p2_region;      // live: B3 -> B4 (disjoint lifetime)
    (void)ws_size; (void)n_in; (void)out_size;

    float* out_h      = (float*)d_out;                      // [N,64]
    float* out_reps   = out_h + (size_t)N * 64;             // [128,64]
    float* out_logits = out_reps + (size_t)NGRAPH * 64;     // [128,16]

    const int GS = 2048;                 // grid-stride blocks (8192 waves)

    hipMemsetAsync(d_ws, 0, zero_bytes, stream);
    // B1 histogram (256 blocks) + graph-independent proj (GS blocks), one launch
    projB1_kernel<<<256 + GS, 256, 0, stream>>>(ei, bucket_cnt, x, W1, P1, E, N, nb);
    bucket_scatter_kernel<<<256, 256, 0, stream>>>(ei, bucket_cnt, bucket_cur,
                                                   pairbuf, E, N, nb);
    bucket_build_kernel<<<nb, 256, 0, stream>>>(pairbuf, bucket_cnt, row_start, dinv,
                                                csr_src, E, N, nb);

    agg_proj_kernel<<<GS, 256, 0, stream>>>(P1, row_start, csr_src, dinv, b1, W2, P2, N);
    agg_pool_kernel<<<GS, 256, 0, stream>>>(P2, row_start, csr_src, dinv, b2, batch,
                                            out_h, accum, N);
    final_kernel<<<NGRAPH, 64, 0, stream>>>(accum, batch, Wc1, bc1, Wc2, bc2,
                                            out_reps, out_logits, N);
}